// Round 1
// baseline (691.159 us; speedup 1.0000x reference)
//
#include <hip/hip_runtime.h>
#include <cstdint>
#include <cstddef>

#define B_DIM 16
#define N_DIM 2048
#define D_DIM 64
#define BN (B_DIM * N_DIM)   // 32768 rows per modality

typedef __attribute__((ext_vector_type(4))) float f32x4;
typedef __attribute__((ext_vector_type(8))) __bf16 bf16x8;

__device__ __forceinline__ unsigned short f2bf(float f) {
    union { float f; unsigned int u; } v; v.f = f;
    unsigned int u = v.u;
    unsigned int r = (u + 0x7fffu + ((u >> 16) & 1u)) >> 16;
    return (unsigned short)r;
}

// ---------------------------------------------------------------------------
// prep: Q_m = x_m @ W_m ; K_m = x_m @ W_m^T ; X_m -> bf16 copy
// grid: 3 * (BN/64) blocks of 256 threads; each block does 64 rows, 1 modality
// ---------------------------------------------------------------------------
__global__ __launch_bounds__(256) void prep_kernel(
    const float* __restrict__ x0, const float* __restrict__ x1, const float* __restrict__ x2,
    const float* __restrict__ w0, const float* __restrict__ w1, const float* __restrict__ w2,
    unsigned short* __restrict__ Qbf, unsigned short* __restrict__ Kbf,
    unsigned short* __restrict__ Xbf)
{
    __shared__ float Ws[64 * 64];   // W[d][c]
    __shared__ float Wt[64 * 64];   // Wt[d][c] = W[c][d]
    __shared__ float xs[64 * 65];   // padded rows (bank-conflict break)

    int m    = blockIdx.x / (BN / 64);
    int tile = blockIdx.x % (BN / 64);
    int row0 = tile * 64;
    const float* x = (m == 0) ? x0 : (m == 1) ? x1 : x2;
    const float* W = (m == 0) ? w0 : (m == 1) ? w1 : w2;
    int tid = threadIdx.x;

    for (int k = 0; k < 16; ++k) {
        int idx = k * 256 + tid;        // 0..4095
        float wv = W[idx];
        Ws[idx] = wv;
        int r = idx >> 6, c = idx & 63;
        Wt[c * 64 + r] = wv;
        float xv = x[(size_t)row0 * 64 + idx];
        xs[r * 65 + c] = xv;
        Xbf[((size_t)m * BN + row0) * 64 + idx] = f2bf(xv);
    }
    __syncthreads();

    int r  = tid >> 2;          // row in tile, 0..63
    int c0 = (tid & 3) * 16;    // col chunk
    float accQ[16], accK[16];
    #pragma unroll
    for (int c = 0; c < 16; ++c) { accQ[c] = 0.f; accK[c] = 0.f; }

    for (int d = 0; d < 64; ++d) {
        float xv = xs[r * 65 + d];
        #pragma unroll
        for (int c = 0; c < 16; ++c) {
            accQ[c] = fmaf(xv, Ws[d * 64 + c0 + c], accQ[c]);   // x @ W
            accK[c] = fmaf(xv, Wt[d * 64 + c0 + c], accK[c]);   // x @ W^T
        }
    }
    size_t base = ((size_t)m * BN + row0 + r) * 64 + c0;
    #pragma unroll
    for (int c = 0; c < 16; ++c) {
        Qbf[base + c] = f2bf(accQ[c]);
        Kbf[base + c] = f2bf(accK[c]);
    }
}

// ---------------------------------------------------------------------------
// attention: block per (modality i, batch b, 64-row Q tile). 256 thr = 4 waves,
// wave w owns q-rows [16w,16w+16). Flash online-softmax over 32 key tiles for
// each of the two pairs j != i. Writes partial_i (pre-mean sum of both pairs).
// ---------------------------------------------------------------------------
__global__ __launch_bounds__(256) void attn_kernel(
    const unsigned short* __restrict__ Qbf,
    const unsigned short* __restrict__ Kbf,
    const unsigned short* __restrict__ Xbf,
    float* __restrict__ partial)
{
    // All tiles padded to stride 72 bf16 (144 B rows -> 2-way bank alias, free)
    __shared__ unsigned short Qs[64 * 72];       // [qrow][d]
    __shared__ unsigned short Ks[64 * 72];       // [key][d]
    __shared__ unsigned short Vs[64 * 72];       // [d][key]  (transposed V)
    __shared__ unsigned short Ps[4][16 * 72];    // per-wave P relayout buffer

    int blk = blockIdx.x;
    int i   = blk / (B_DIM * 32);
    int rem = blk % (B_DIM * 32);
    int b   = rem / 32;
    int qt  = rem % 32;
    int q0  = qt * 64;

    int tid  = threadIdx.x;
    int wave = tid >> 6;
    int lane = tid & 63;
    int lq   = lane & 15;
    int quad = lane >> 4;

    // stage Q tile
    const unsigned short* Qg = Qbf + ((size_t)i * BN + (size_t)b * N_DIM + q0) * 64;
    #pragma unroll
    for (int k = 0; k < 2; ++k) {
        int ch = k * 256 + tid;             // 16B chunk id, 0..511
        int rr = ch >> 3, c0 = (ch & 7) * 8;
        *(uint4*)&Qs[rr * 72 + c0] = *(const uint4*)&Qg[rr * 64 + c0];
    }
    __syncthreads();

    // preload A-fragments of Q (constant across the whole kernel)
    bf16x8 qf[2];
    qf[0] = __builtin_bit_cast(bf16x8, *(const uint4*)&Qs[(wave * 16 + lq) * 72 + 0  + quad * 8]);
    qf[1] = __builtin_bit_cast(bf16x8, *(const uint4*)&Qs[(wave * 16 + lq) * 72 + 32 + quad * 8]);

    f32x4 tot[4];
    #pragma unroll
    for (int f = 0; f < 4; ++f) tot[f] = (f32x4){0.f, 0.f, 0.f, 0.f};

    for (int jj = 0; jj < 2; ++jj) {
        int j = (i + 1 + jj) % 3;
        const unsigned short* Kg = Kbf + ((size_t)j * BN + (size_t)b * N_DIM) * 64;
        const unsigned short* Vg = Xbf + ((size_t)j * BN + (size_t)b * N_DIM) * 64;

        float m_r[4], l_r[4];
        f32x4 O[4];
        #pragma unroll
        for (int rr = 0; rr < 4; ++rr) { m_r[rr] = -1e30f; l_r[rr] = 0.f; }
        #pragma unroll
        for (int f = 0; f < 4; ++f) O[f] = (f32x4){0.f, 0.f, 0.f, 0.f};

        for (int kt = 0; kt < 32; ++kt) {
            __syncthreads();   // previous tile's LDS reads done before overwrite
            #pragma unroll
            for (int k = 0; k < 2; ++k) {
                int ch = k * 256 + tid;
                int rr = ch >> 3, c0 = (ch & 7) * 8;    // rr = key, c0 = d chunk
                *(uint4*)&Ks[rr * 72 + c0] =
                    *(const uint4*)&Kg[((size_t)(kt * 64 + rr)) * 64 + c0];
                union { uint4 u; unsigned short s[8]; } cv;
                cv.u = *(const uint4*)&Vg[((size_t)(kt * 64 + rr)) * 64 + c0];
                #pragma unroll
                for (int e = 0; e < 8; ++e) Vs[(c0 + e) * 72 + rr] = cv.s[e];
            }
            __syncthreads();

            // S = (Q K^T) * scale   -- 4 key-frags x 2 d-chunks
            f32x4 s[4];
            #pragma unroll
            for (int f = 0; f < 4; ++f) {
                f32x4 acc = (f32x4){0.f, 0.f, 0.f, 0.f};
                #pragma unroll
                for (int c = 0; c < 2; ++c) {
                    bf16x8 bfrag = __builtin_bit_cast(bf16x8,
                        *(const uint4*)&Ks[(f * 16 + lq) * 72 + c * 32 + quad * 8]);
                    acc = __builtin_amdgcn_mfma_f32_16x16x32_bf16(qf[c], bfrag, acc, 0, 0, 0);
                }
                s[f] = acc;
            }
            #pragma unroll
            for (int f = 0; f < 4; ++f)
                #pragma unroll
                for (int rr = 0; rr < 4; ++rr)
                    s[f][rr] *= 0.125f;

            // online softmax: row max across 16 lanes of same quad-group
            float mnew[4], alpha[4];
            #pragma unroll
            for (int rr = 0; rr < 4; ++rr) {
                float mm = fmaxf(fmaxf(s[0][rr], s[1][rr]), fmaxf(s[2][rr], s[3][rr]));
                #pragma unroll
                for (int off = 8; off > 0; off >>= 1)
                    mm = fmaxf(mm, __shfl_xor(mm, off));
                float mn = fmaxf(m_r[rr], mm);
                mnew[rr]  = mn;
                alpha[rr] = __expf(m_r[rr] - mn);
                m_r[rr]   = mn;
            }
            // P = exp(s - mnew); write to per-wave LDS in A-operand layout
            #pragma unroll
            for (int f = 0; f < 4; ++f) {
                #pragma unroll
                for (int rr = 0; rr < 4; ++rr) {
                    float p = __expf(s[f][rr] - mnew[rr]);
                    s[f][rr] = p;
                    Ps[wave][(quad * 4 + rr) * 72 + f * 16 + lq] = f2bf(p);
                }
            }
            #pragma unroll
            for (int rr = 0; rr < 4; ++rr) {
                float sum = s[0][rr] + s[1][rr] + s[2][rr] + s[3][rr];
                #pragma unroll
                for (int off = 8; off > 0; off >>= 1)
                    sum += __shfl_xor(sum, off);
                l_r[rr] = l_r[rr] * alpha[rr] + sum;
                #pragma unroll
                for (int f = 0; f < 4; ++f)
                    O[f][rr] *= alpha[rr];
            }
            // O += P @ V   (A = P from LDS, B = V^T tile, contiguous b128 reads)
            #pragma unroll
            for (int c = 0; c < 2; ++c) {
                bf16x8 pa = __builtin_bit_cast(bf16x8,
                    *(const uint4*)&Ps[wave][lq * 72 + c * 32 + quad * 8]);
                #pragma unroll
                for (int f = 0; f < 4; ++f) {
                    bf16x8 vb = __builtin_bit_cast(bf16x8,
                        *(const uint4*)&Vs[(f * 16 + lq) * 72 + c * 32 + quad * 8]);
                    O[f] = __builtin_amdgcn_mfma_f32_16x16x32_bf16(pa, vb, O[f], 0, 0, 0);
                }
            }
        }
        #pragma unroll
        for (int rr = 0; rr < 4; ++rr) {
            float inv = 1.0f / l_r[rr];
            #pragma unroll
            for (int f = 0; f < 4; ++f)
                tot[f][rr] += O[f][rr] * inv;
        }
    }

    float* po = partial + ((size_t)i * BN + (size_t)b * N_DIM + q0) * 64;
    #pragma unroll
    for (int rr = 0; rr < 4; ++rr) {
        int row = wave * 16 + quad * 4 + rr;
        #pragma unroll
        for (int f = 0; f < 4; ++f)
            po[row * 64 + f * 16 + lq] = tot[f][rr];
    }
}

// ---------------------------------------------------------------------------
// reduce: out = (p0 + p1 + p2) / 3, vectorized
// ---------------------------------------------------------------------------
__global__ __launch_bounds__(256) void reduce_kernel(
    const float* __restrict__ partial, float* __restrict__ out)
{
    size_t idx = (size_t)blockIdx.x * blockDim.x + threadIdx.x;   // float4 index
    const f32x4* p0 = (const f32x4*)partial;
    const f32x4* p1 = p0 + (size_t)BN * 64 / 4;
    const f32x4* p2 = p1 + (size_t)BN * 64 / 4;
    f32x4 v = (p0[idx] + p1[idx] + p2[idx]) * (1.0f / 3.0f);
    ((f32x4*)out)[idx] = v;
}

extern "C" void kernel_launch(void* const* d_in, const int* in_sizes, int n_in,
                              void* d_out, int out_size, void* d_ws, size_t ws_size,
                              hipStream_t stream)
{
    const float* x0 = (const float*)d_in[0];
    const float* x1 = (const float*)d_in[1];
    const float* x2 = (const float*)d_in[2];
    const float* w0 = (const float*)d_in[3];
    const float* w1 = (const float*)d_in[4];
    const float* w2 = (const float*)d_in[5];
    float* out = (float*)d_out;

    // workspace layout (bytes): Qbf 12.58M | Kbf 12.58M | Xbf 12.58M | partial 25.17M
    size_t nElem = (size_t)3 * BN * 64;               // 6,291,456 bf16 per tensor
    unsigned short* Qbf = (unsigned short*)d_ws;
    unsigned short* Kbf = Qbf + nElem;
    unsigned short* Xbf = Kbf + nElem;
    float* partial = (float*)(Xbf + nElem);           // 3 * BN * 64 floats

    hipLaunchKernelGGL(prep_kernel, dim3(3 * BN / 64), dim3(256), 0, stream,
                       x0, x1, x2, w0, w1, w2, Qbf, Kbf, Xbf);
    hipLaunchKernelGGL(attn_kernel, dim3(3 * B_DIM * (N_DIM / 64)), dim3(256), 0, stream,
                       Qbf, Kbf, Xbf, partial);
    hipLaunchKernelGGL(reduce_kernel, dim3(BN * 64 / 4 / 256), dim3(256), 0, stream,
                       partial, out);
}

// Round 2
// 283.287 us; speedup vs baseline: 2.4398x; 2.4398x over previous
//
#include <hip/hip_runtime.h>
#include <cstdint>
#include <cstddef>

#define B_DIM 16
#define N_DIM 2048
#define BN (B_DIM * N_DIM)          // 32768 rows per modality
#define QSCALE 0.18033688f          // 0.125 * log2(e): folded so P = exp2(S')

typedef __attribute__((ext_vector_type(4))) float f32x4;
typedef __attribute__((ext_vector_type(8))) __bf16 bf16x8;

__device__ __forceinline__ unsigned short f2bf_rne(float f) {
    union { float f; unsigned int u; } v; v.f = f;
    unsigned int u = v.u;
    return (unsigned short)((u + 0x7fffu + ((u >> 16) & 1u)) >> 16);
}

// ---------------------------------------------------------------------------
// prep: Qbf = (x@W) * QSCALE ; Kbf = x@W^T ; Vt = x^T per (m,b): [m][b][d][n]
// ---------------------------------------------------------------------------
__global__ __launch_bounds__(256) void prep_kernel(
    const float* __restrict__ x0, const float* __restrict__ x1, const float* __restrict__ x2,
    const float* __restrict__ w0, const float* __restrict__ w1, const float* __restrict__ w2,
    unsigned short* __restrict__ Qbf, unsigned short* __restrict__ Kbf,
    unsigned short* __restrict__ Vt)
{
    __shared__ float Ws[64 * 64];   // W[d][c]
    __shared__ float Wt[64 * 64];   // W^T
    __shared__ float xs[64 * 65];   // x rows, padded

    int m    = blockIdx.x / (BN / 64);
    int tile = blockIdx.x % (BN / 64);
    int row0 = tile * 64;
    int b    = row0 >> 11;          // row0 / 2048
    int n0   = row0 & 2047;
    const float* x = (m == 0) ? x0 : (m == 1) ? x1 : x2;
    const float* W = (m == 0) ? w0 : (m == 1) ? w1 : w2;
    int tid = threadIdx.x;

    for (int k = 0; k < 16; ++k) {
        int idx = k * 256 + tid;
        float wv = W[idx];
        Ws[idx] = wv;
        int r = idx >> 6, c = idx & 63;
        Wt[c * 64 + r] = wv;
        xs[r * 65 + c] = x[(size_t)row0 * 64 + idx];
    }
    __syncthreads();

    int r  = tid >> 2;
    int cg = tid & 3;
    int c0 = cg * 16;
    float accQ[16], accK[16];
    #pragma unroll
    for (int c = 0; c < 16; ++c) { accQ[c] = 0.f; accK[c] = 0.f; }

    for (int d = 0; d < 64; ++d) {
        float xv = xs[r * 65 + d];
        #pragma unroll
        for (int c = 0; c < 16; ++c) {
            accQ[c] = fmaf(xv, Ws[d * 64 + c0 + c], accQ[c]);
            accK[c] = fmaf(xv, Wt[d * 64 + c0 + c], accK[c]);
        }
    }

    // packed stores of Q (scaled) and K
    unsigned int uq[8], uk[8];
    #pragma unroll
    for (int c = 0; c < 8; ++c) {
        unsigned int q0s = f2bf_rne(accQ[2 * c] * QSCALE);
        unsigned int q1s = f2bf_rne(accQ[2 * c + 1] * QSCALE);
        uq[c] = q0s | (q1s << 16);
        unsigned int k0s = f2bf_rne(accK[2 * c]);
        unsigned int k1s = f2bf_rne(accK[2 * c + 1]);
        uk[c] = k0s | (k1s << 16);
    }
    size_t base = ((size_t)m * BN + row0 + r) * 64 + c0;
    *(uint4*)&Qbf[base]     = *(uint4*)&uq[0];
    *(uint4*)&Qbf[base + 8] = *(uint4*)&uq[4];
    *(uint4*)&Kbf[base]     = *(uint4*)&uk[0];
    *(uint4*)&Kbf[base + 8] = *(uint4*)&uk[4];

    // V^T: thread (d=r, cg) writes Vt[d][n0+c0 .. +16]
    unsigned int uv[8];
    #pragma unroll
    for (int c = 0; c < 8; ++c) {
        unsigned int v0s = f2bf_rne(xs[(c0 + 2 * c) * 65 + r]);
        unsigned int v1s = f2bf_rne(xs[(c0 + 2 * c + 1) * 65 + r]);
        uv[c] = v0s | (v1s << 16);
    }
    size_t vbase = ((size_t)(m * B_DIM + b) * 64 + r) * 2048 + n0 + c0;
    *(uint4*)&Vt[vbase]     = *(uint4*)&uv[0];
    *(uint4*)&Vt[vbase + 8] = *(uint4*)&uv[4];
}

// ---------------------------------------------------------------------------
// attention: block = 4 waves, each wave 32 q-rows (2 x 16-row subtiles);
// block covers 128 q-rows. S^T = K Q^T (no max-tracking softmax, deferred l),
// O^T = V^T P^T. K/V LDS tiles XOR-chunk-swizzled, stride 64.
// ---------------------------------------------------------------------------
__global__ __launch_bounds__(256) void attn_kernel(
    const unsigned short* __restrict__ Qbf,
    const unsigned short* __restrict__ Kbf,
    const unsigned short* __restrict__ Vt,
    float* __restrict__ partial)
{
    __shared__ unsigned short Ks[64 * 64];       // [key][d], chunk-swizzled
    __shared__ unsigned short Vs[64 * 64];       // [d][key], chunk-swizzled
    __shared__ unsigned short Ps[4][32 * 72];    // per-wave P [q][key], plain

    int blk = blockIdx.x;
    int i   = blk / (B_DIM * 16);
    int rem = blk % (B_DIM * 16);
    int b   = rem / 16;
    int qt  = rem % 16;
    int q0  = qt * 128;

    int tid  = threadIdx.x;
    int wave = tid >> 6;
    int lane = tid & 63;
    int lq   = lane & 15;
    int quad = lane >> 4;
    int sw   = lq & 7;               // XOR swizzle key for this lane's rows

    // Q fragments (B operand: rows [q][d]) straight from global
    const unsigned short* Qg = Qbf + ((size_t)i * BN + b * N_DIM + q0 + wave * 32) * 64;
    bf16x8 qf[2][2];
    #pragma unroll
    for (int sub = 0; sub < 2; ++sub)
        #pragma unroll
        for (int c = 0; c < 2; ++c)
            qf[sub][c] = __builtin_bit_cast(bf16x8,
                *(const uint4*)&Qg[(sub * 16 + lq) * 64 + c * 32 + quad * 8]);

    f32x4 tot[2][4];
    #pragma unroll
    for (int s = 0; s < 2; ++s)
        #pragma unroll
        for (int v = 0; v < 4; ++v)
            tot[s][v] = (f32x4){0.f, 0.f, 0.f, 0.f};

    for (int jj = 0; jj < 2; ++jj) {
        int j = (i + 1 + jj) % 3;
        const unsigned short* Kg = Kbf + ((size_t)j * BN + b * N_DIM) * 64;
        const unsigned short* Vg = Vt + ((size_t)(j * B_DIM + b) * 64) * 2048;

        f32x4 O[2][4];
        #pragma unroll
        for (int s = 0; s < 2; ++s)
            #pragma unroll
            for (int v = 0; v < 4; ++v)
                O[s][v] = (f32x4){0.f, 0.f, 0.f, 0.f};
        float lsum[2] = {0.f, 0.f};

        for (int kt = 0; kt < 32; ++kt) {
            __syncthreads();
            #pragma unroll
            for (int k2 = 0; k2 < 2; ++k2) {
                int ch = k2 * 256 + tid;
                int r  = ch >> 3, c8 = ch & 7;
                *(uint4*)&Ks[r * 64 + ((c8 ^ (r & 7)) * 8)] =
                    *(const uint4*)&Kg[(size_t)(kt * 64 + r) * 64 + c8 * 8];
                *(uint4*)&Vs[r * 64 + ((c8 ^ (r & 7)) * 8)] =
                    *(const uint4*)&Vg[(size_t)r * 2048 + kt * 64 + c8 * 8];
            }
            __syncthreads();

            // S^T = K Q^T  (A = K rows, B = Q rows)
            f32x4 st[2][4];
            #pragma unroll
            for (int s = 0; s < 2; ++s)
                #pragma unroll
                for (int f = 0; f < 4; ++f)
                    st[s][f] = (f32x4){0.f, 0.f, 0.f, 0.f};
            #pragma unroll
            for (int c = 0; c < 2; ++c) {
                bf16x8 kf[4];
                #pragma unroll
                for (int f = 0; f < 4; ++f)
                    kf[f] = __builtin_bit_cast(bf16x8,
                        *(const uint4*)&Ks[(f * 16 + lq) * 64 + (((c * 4 + quad) ^ sw) * 8)]);
                #pragma unroll
                for (int s = 0; s < 2; ++s)
                    #pragma unroll
                    for (int f = 0; f < 4; ++f)
                        st[s][f] = __builtin_amdgcn_mfma_f32_16x16x32_bf16(
                            kf[f], qf[s][c], st[s][f], 0, 0, 0);
            }

            // P = exp2(S'), truncate-pack to bf16 pairs, write [q][key]
            #pragma unroll
            for (int s = 0; s < 2; ++s) {
                #pragma unroll
                for (int f = 0; f < 4; ++f) {
                    float p0 = __builtin_amdgcn_exp2f(st[s][f][0]);
                    float p1 = __builtin_amdgcn_exp2f(st[s][f][1]);
                    float p2 = __builtin_amdgcn_exp2f(st[s][f][2]);
                    float p3 = __builtin_amdgcn_exp2f(st[s][f][3]);
                    lsum[s] += (p0 + p1) + (p2 + p3);
                    unsigned int u0 = __builtin_bit_cast(unsigned int, p0);
                    unsigned int u1 = __builtin_bit_cast(unsigned int, p1);
                    unsigned int u2 = __builtin_bit_cast(unsigned int, p2);
                    unsigned int u3 = __builtin_bit_cast(unsigned int, p3);
                    unsigned int d0 = __builtin_amdgcn_perm(u1, u0, 0x07060302u);
                    unsigned int d1 = __builtin_amdgcn_perm(u3, u2, 0x07060302u);
                    unsigned short* pp = &Ps[wave][(s * 16 + lq) * 72 + f * 16 + quad * 4];
                    *(unsigned int*)pp       = d0;
                    *(unsigned int*)(pp + 2) = d1;
                }
            }

            // O^T += V^T P^T  (A = V^T rows from Vs, B = P rows from Ps)
            #pragma unroll
            for (int c = 0; c < 2; ++c) {
                bf16x8 pb0 = __builtin_bit_cast(bf16x8,
                    *(const uint4*)&Ps[wave][(0 * 16 + lq) * 72 + c * 32 + quad * 8]);
                bf16x8 pb1 = __builtin_bit_cast(bf16x8,
                    *(const uint4*)&Ps[wave][(1 * 16 + lq) * 72 + c * 32 + quad * 8]);
                #pragma unroll
                for (int vf = 0; vf < 4; ++vf) {
                    bf16x8 av = __builtin_bit_cast(bf16x8,
                        *(const uint4*)&Vs[(vf * 16 + lq) * 64 + (((c * 4 + quad) ^ sw) * 8)]);
                    O[0][vf] = __builtin_amdgcn_mfma_f32_16x16x32_bf16(av, pb0, O[0][vf], 0, 0, 0);
                    O[1][vf] = __builtin_amdgcn_mfma_f32_16x16x32_bf16(av, pb1, O[1][vf], 0, 0, 0);
                }
            }
        }

        // deferred l reduction (across the 4 quad lanes holding this q-col)
        #pragma unroll
        for (int s = 0; s < 2; ++s) {
            float l = lsum[s];
            l += __shfl_xor(l, 16);
            l += __shfl_xor(l, 32);
            float inv = 1.0f / l;
            #pragma unroll
            for (int vf = 0; vf < 4; ++vf)
                #pragma unroll
                for (int rr = 0; rr < 4; ++rr)
                    tot[s][vf][rr] += O[s][vf][rr] * inv;
        }
    }

    // store: O^T C-layout -> partial[q][d], f32x4 along d
    float* po = partial + ((size_t)i * BN + b * N_DIM + q0 + wave * 32) * 64;
    #pragma unroll
    for (int s = 0; s < 2; ++s)
        #pragma unroll
        for (int vf = 0; vf < 4; ++vf)
            *(f32x4*)&po[(s * 16 + lq) * 64 + vf * 16 + quad * 4] = tot[s][vf];
}

// ---------------------------------------------------------------------------
// reduce: out = (p0 + p1 + p2) / 3
// ---------------------------------------------------------------------------
__global__ __launch_bounds__(256) void reduce_kernel(
    const float* __restrict__ partial, float* __restrict__ out)
{
    size_t idx = (size_t)blockIdx.x * blockDim.x + threadIdx.x;
    const f32x4* p0 = (const f32x4*)partial;
    const f32x4* p1 = p0 + (size_t)BN * 64 / 4;
    const f32x4* p2 = p1 + (size_t)BN * 64 / 4;
    f32x4 v = (p0[idx] + p1[idx] + p2[idx]) * (1.0f / 3.0f);
    ((f32x4*)out)[idx] = v;
}

extern "C" void kernel_launch(void* const* d_in, const int* in_sizes, int n_in,
                              void* d_out, int out_size, void* d_ws, size_t ws_size,
                              hipStream_t stream)
{
    const float* x0 = (const float*)d_in[0];
    const float* x1 = (const float*)d_in[1];
    const float* x2 = (const float*)d_in[2];
    const float* w0 = (const float*)d_in[3];
    const float* w1 = (const float*)d_in[4];
    const float* w2 = (const float*)d_in[5];
    float* out = (float*)d_out;

    size_t nElem = (size_t)3 * BN * 64;
    unsigned short* Qbf = (unsigned short*)d_ws;
    unsigned short* Kbf = Qbf + nElem;
    unsigned short* Vt  = Kbf + nElem;
    float* partial = (float*)(Vt + nElem);

    hipLaunchKernelGGL(prep_kernel, dim3(3 * BN / 64), dim3(256), 0, stream,
                       x0, x1, x2, w0, w1, w2, Qbf, Kbf, Vt);
    hipLaunchKernelGGL(attn_kernel, dim3(3 * B_DIM * 16), dim3(256), 0, stream,
                       Qbf, Kbf, Vt, partial);
    hipLaunchKernelGGL(reduce_kernel, dim3(BN * 64 / 4 / 256), dim3(256), 0, stream,
                       partial, out);
}

// Round 3
// 229.762 us; speedup vs baseline: 3.0082x; 1.2330x over previous
//
#include <hip/hip_runtime.h>
#include <cstdint>
#include <cstddef>

#define B_DIM 16
#define N_DIM 2048
#define BN (B_DIM * N_DIM)          // 32768 rows per modality
#define QSCALE 0.18033688f          // 0.125 * log2(e): P = exp2(S')
#define PLANE ((size_t)BN * 64)     // elems per (jj,i) partial plane

typedef __attribute__((ext_vector_type(4))) float f32x4;
typedef __attribute__((ext_vector_type(16))) float f32x16;
typedef __attribute__((ext_vector_type(8))) __bf16 bf16x8;
typedef __attribute__((ext_vector_type(2))) unsigned int u32x2;

__device__ __forceinline__ unsigned short f2bf_rne(float f) {
    union { float f; unsigned int u; } v; v.f = f;
    unsigned int u = v.u;
    return (unsigned short)((u + 0x7fffu + ((u >> 16) & 1u)) >> 16);
}
__device__ __forceinline__ unsigned pk_rne(float a, float b) {
    return (unsigned)f2bf_rne(a) | ((unsigned)f2bf_rne(b) << 16);
}
// half_swap(a,b): res.x = {a.lo32, b.lo32}, res.y = {a.hi32, b.hi32}
__device__ __forceinline__ u32x2 half_swap(unsigned a, unsigned b) {
#if __has_builtin(__builtin_amdgcn_permlane32_swap)
    return __builtin_amdgcn_permlane32_swap(a, b, false, false);
#else
    unsigned pa = (unsigned)__shfl_xor((int)a, 32);
    unsigned pb = (unsigned)__shfl_xor((int)b, 32);
    bool hi = (threadIdx.x & 32) != 0;
    u32x2 r;
    r.x = hi ? pb : a;
    r.y = hi ? b : pa;
    return r;
#endif
}

// ---------------------------------------------------------------------------
// prep (MFMA): Q = (x@W)*QSCALE, K = x@W^T  (bf16 rows), Vt = x^T (bf16, [m][b][d][n])
// block = 256 thr, 128 x-rows; wave w owns rows 32w..32w+31
// ---------------------------------------------------------------------------
__global__ __launch_bounds__(256) void prep_kernel(
    const float* __restrict__ x0, const float* __restrict__ x1, const float* __restrict__ x2,
    const float* __restrict__ w0, const float* __restrict__ w1, const float* __restrict__ w2,
    unsigned short* __restrict__ Qbf, unsigned short* __restrict__ Kbf,
    unsigned short* __restrict__ Vt)
{
    __shared__ float Wf[64 * 64];
    __shared__ float xs[128 * 68];      // stride 68: 16B-aligned rows, mild bank rotation

    int m    = blockIdx.x >> 8;         // 256 tiles per modality
    int tile = blockIdx.x & 255;
    int row0 = tile * 128;
    int b    = row0 >> 11;
    int n0   = row0 & 2047;
    const float* x = (m == 0) ? x0 : (m == 1) ? x1 : x2;
    const float* W = (m == 0) ? w0 : (m == 1) ? w1 : w2;
    int tid = threadIdx.x;

    #pragma unroll
    for (int v = 0; v < 4; ++v) {
        int i4 = v * 256 + tid;
        *(f32x4*)&Wf[i4 * 4] = *(const f32x4*)&W[i4 * 4];
    }
    #pragma unroll
    for (int v = 0; v < 8; ++v) {
        int i4 = v * 256 + tid;
        int r = i4 >> 4, c = (i4 & 15) * 4;
        *(f32x4*)&xs[r * 68 + c] = *(const f32x4*)&x[(size_t)row0 * 64 + i4 * 4];
    }
    __syncthreads();

    int lane = tid & 63, wave = tid >> 6, lq = lane & 31, h = lane >> 5;

    // A-frags: wq[m=e][k=d] = W[d][e]*QSCALE ; wk[m=e][k=d] = W[e][d]
    bf16x8 wq[2][4], wk[2][4];
    #pragma unroll
    for (int mf = 0; mf < 2; ++mf)
        #pragma unroll
        for (int kc = 0; kc < 4; ++kc) {
            int e  = mf * 32 + lq;
            int d0 = kc * 16 + h * 8;
            unsigned uq[4], uk[4];
            #pragma unroll
            for (int t = 0; t < 4; ++t) {
                int d = d0 + 2 * t;
                uq[t] = pk_rne(Wf[d * 64 + e] * QSCALE, Wf[(d + 1) * 64 + e] * QSCALE);
                uk[t] = pk_rne(Wf[e * 64 + d], Wf[e * 64 + d + 1]);
            }
            uint4 ua; ua.x = uq[0]; ua.y = uq[1]; ua.z = uq[2]; ua.w = uq[3];
            uint4 ub; ub.x = uk[0]; ub.y = uk[1]; ub.z = uk[2]; ub.w = uk[3];
            wq[mf][kc] = __builtin_bit_cast(bf16x8, ua);
            wk[mf][kc] = __builtin_bit_cast(bf16x8, ub);
        }

    // B-frags: xb[k=d][n=row] = x[row][d], row = 32*wave + lq
    bf16x8 xb[4];
    #pragma unroll
    for (int kc = 0; kc < 4; ++kc) {
        const float* xr = &xs[(wave * 32 + lq) * 68 + kc * 16 + h * 8];
        unsigned u[4];
        #pragma unroll
        for (int t = 0; t < 4; ++t) u[t] = pk_rne(xr[2 * t], xr[2 * t + 1]);
        uint4 ua; ua.x = u[0]; ua.y = u[1]; ua.z = u[2]; ua.w = u[3];
        xb[kc] = __builtin_bit_cast(bf16x8, ua);
    }

    f32x16 Qt[2], Kt[2];
    #pragma unroll
    for (int r = 0; r < 16; ++r) { Qt[0][r] = 0.f; Qt[1][r] = 0.f; Kt[0][r] = 0.f; Kt[1][r] = 0.f; }
    #pragma unroll
    for (int kc = 0; kc < 4; ++kc) {
        #pragma unroll
        for (int mf = 0; mf < 2; ++mf) {
            Qt[mf] = __builtin_amdgcn_mfma_f32_32x32x16_bf16(wq[mf][kc], xb[kc], Qt[mf], 0, 0, 0);
            Kt[mf] = __builtin_amdgcn_mfma_f32_32x32x16_bf16(wk[mf][kc], xb[kc], Kt[mf], 0, 0, 0);
        }
    }

    // store rows: lane holds col n = 32*wave+lq; e = 32*mf + (r&3)+8*(r>>2)+4h
    size_t rowidx = (size_t)m * BN + row0 + wave * 32 + lq;
    unsigned short* qdst = Qbf + rowidx * 64 + h * 32;
    unsigned short* kdst = Kbf + rowidx * 64 + h * 32;
    #pragma unroll
    for (int s = 0; s < 4; ++s) {
        unsigned q00 = pk_rne(Qt[0][4 * s], Qt[0][4 * s + 1]);
        unsigned q01 = pk_rne(Qt[0][4 * s + 2], Qt[0][4 * s + 3]);
        unsigned q10 = pk_rne(Qt[1][4 * s], Qt[1][4 * s + 1]);
        unsigned q11 = pk_rne(Qt[1][4 * s + 2], Qt[1][4 * s + 3]);
        u32x2 a = half_swap(q00, q10);
        u32x2 c = half_swap(q01, q11);
        uint4 w; w.x = a.x; w.y = c.x; w.z = a.y; w.w = c.y;
        *(uint4*)&qdst[s * 8] = w;

        unsigned k00 = pk_rne(Kt[0][4 * s], Kt[0][4 * s + 1]);
        unsigned k01 = pk_rne(Kt[0][4 * s + 2], Kt[0][4 * s + 3]);
        unsigned k10 = pk_rne(Kt[1][4 * s], Kt[1][4 * s + 1]);
        unsigned k11 = pk_rne(Kt[1][4 * s + 2], Kt[1][4 * s + 3]);
        u32x2 a2 = half_swap(k00, k10);
        u32x2 c2 = half_swap(k01, k11);
        uint4 w2; w2.x = a2.x; w2.y = c2.x; w2.z = a2.y; w2.w = c2.y;
        *(uint4*)&kdst[s * 8] = w2;
    }

    // Vt: thread owns d = tid&63, n-range 32*(tid>>6)..+31
    int d  = tid & 63;
    int ng = tid >> 6;
    unsigned short* vdst = Vt + ((size_t)(m * B_DIM + b) * 64 + d) * 2048 + n0 + ng * 32;
    #pragma unroll
    for (int s = 0; s < 4; ++s) {
        uint4 w;
        w.x = pk_rne(xs[(ng * 32 + 8 * s + 0) * 68 + d], xs[(ng * 32 + 8 * s + 1) * 68 + d]);
        w.y = pk_rne(xs[(ng * 32 + 8 * s + 2) * 68 + d], xs[(ng * 32 + 8 * s + 3) * 68 + d]);
        w.z = pk_rne(xs[(ng * 32 + 8 * s + 4) * 68 + d], xs[(ng * 32 + 8 * s + 5) * 68 + d]);
        w.w = pk_rne(xs[(ng * 32 + 8 * s + 6) * 68 + d], xs[(ng * 32 + 8 * s + 7) * 68 + d]);
        *(uint4*)&vdst[s * 8] = w;
    }
}

// ---------------------------------------------------------------------------
// attention: block = one (pair, b, 256-q tile); 4 waves x 64 q-rows each.
// S^T = K Q^T (32x32x16), P relayout via permlane32_swap, O^T = V^T P^T.
// Writes bf16 partial plane (jj,i), rows [q][d].
// ---------------------------------------------------------------------------
__global__ __launch_bounds__(256, 2) void attn_kernel(
    const unsigned short* __restrict__ Qbf,
    const unsigned short* __restrict__ Kbf,
    const unsigned short* __restrict__ Vt,
    unsigned short* __restrict__ part)
{
    __shared__ unsigned short Ks[64 * 64];   // [key][d], XOR-chunk swizzled
    __shared__ unsigned short Vs[64 * 64];   // [d][key], XOR-chunk swizzled

    int blk = blockIdx.x;                    // 768 = 6 pairs * 16 b * 8 qt
    int qt  = blk & 7;
    int b   = (blk >> 3) & 15;
    int p   = blk >> 7;
    int i   = p >> 1, jj = p & 1;
    int j   = i + 1 + jj; if (j >= 3) j -= 3;
    int q0  = qt * 256;

    int tid = threadIdx.x, wave = tid >> 6, lane = tid & 63;
    int lq = lane & 31, h = lane >> 5;

    // Q B-frags: q = q0 + 64*wave + 32*qi + lq, d = 16*kc + 8*h + j
    const unsigned short* Qg = Qbf + ((size_t)i * BN + b * N_DIM + q0 + wave * 64) * 64;
    bf16x8 qf[2][4];
    #pragma unroll
    for (int qi = 0; qi < 2; ++qi)
        #pragma unroll
        for (int kc = 0; kc < 4; ++kc)
            qf[qi][kc] = __builtin_bit_cast(bf16x8,
                *(const uint4*)&Qg[(qi * 32 + lq) * 64 + kc * 16 + h * 8]);

    f32x16 O[2][2];                          // [df][qi]
    #pragma unroll
    for (int r = 0; r < 16; ++r) { O[0][0][r] = 0.f; O[0][1][r] = 0.f; O[1][0][r] = 0.f; O[1][1][r] = 0.f; }
    float lsum[2] = {0.f, 0.f};

    const unsigned short* Kg = Kbf + ((size_t)j * BN + b * N_DIM) * 64;
    const unsigned short* Vg = Vt + (size_t)(j * B_DIM + b) * 64 * 2048;

    for (int kt = 0; kt < 32; ++kt) {
        __syncthreads();
        #pragma unroll
        for (int k2 = 0; k2 < 2; ++k2) {
            int ch = k2 * 256 + tid;
            int r = ch >> 3, c8 = ch & 7;
            *(uint4*)&Ks[r * 64 + ((c8 ^ (r & 7)) * 8)] =
                *(const uint4*)&Kg[(size_t)(kt * 64 + r) * 64 + c8 * 8];
            *(uint4*)&Vs[r * 64 + ((c8 ^ (r & 7)) * 8)] =
                *(const uint4*)&Vg[(size_t)r * 2048 + kt * 64 + c8 * 8];
        }
        __syncthreads();

        #pragma unroll
        for (int kf = 0; kf < 2; ++kf) {
            // S^T tile: keys 32kf..32kf+31 x 64 q
            f32x16 st[2];
            #pragma unroll
            for (int r = 0; r < 16; ++r) { st[0][r] = 0.f; st[1][r] = 0.f; }
            int key = kf * 32 + lq;
            #pragma unroll
            for (int kc = 0; kc < 4; ++kc) {
                bf16x8 kfr = __builtin_bit_cast(bf16x8,
                    *(const uint4*)&Ks[key * 64 + (((2 * kc + h) ^ (key & 7)) * 8)]);
                st[0] = __builtin_amdgcn_mfma_f32_32x32x16_bf16(kfr, qf[0][kc], st[0], 0, 0, 0);
                st[1] = __builtin_amdgcn_mfma_f32_32x32x16_bf16(kfr, qf[1][kc], st[1], 0, 0, 0);
            }

            // P = exp2(S'), pack bf16 pairs (truncation), keep in regs
            unsigned pkk[2][4][2];
            #pragma unroll
            for (int qi = 0; qi < 2; ++qi)
                #pragma unroll
                for (int s = 0; s < 4; ++s) {
                    float e0 = __builtin_amdgcn_exp2f(st[qi][4 * s + 0]);
                    float e1 = __builtin_amdgcn_exp2f(st[qi][4 * s + 1]);
                    float e2 = __builtin_amdgcn_exp2f(st[qi][4 * s + 2]);
                    float e3 = __builtin_amdgcn_exp2f(st[qi][4 * s + 3]);
                    lsum[qi] += (e0 + e1) + (e2 + e3);
                    pkk[qi][s][0] = __builtin_amdgcn_perm(
                        __builtin_bit_cast(unsigned, e1), __builtin_bit_cast(unsigned, e0), 0x07060302u);
                    pkk[qi][s][1] = __builtin_amdgcn_perm(
                        __builtin_bit_cast(unsigned, e3), __builtin_bit_cast(unsigned, e2), 0x07060302u);
                }

            // assemble P B-frags (half-swap) and do PV
            #pragma unroll
            for (int c = 0; c < 2; ++c) {
                bf16x8 pf[2];
                #pragma unroll
                for (int qi = 0; qi < 2; ++qi) {
                    u32x2 r0 = half_swap(pkk[qi][2 * c][0], pkk[qi][2 * c + 1][0]);
                    u32x2 r1 = half_swap(pkk[qi][2 * c][1], pkk[qi][2 * c + 1][1]);
                    uint4 t; t.x = r0.x; t.y = r1.x; t.z = r0.y; t.w = r1.y;
                    pf[qi] = __builtin_bit_cast(bf16x8, t);
                }
                int kcpv = 2 * kf + c;
                #pragma unroll
                for (int df = 0; df < 2; ++df) {
                    int d = df * 32 + lq;
                    bf16x8 vfr = __builtin_bit_cast(bf16x8,
                        *(const uint4*)&Vs[d * 64 + (((2 * kcpv + h) ^ (d & 7)) * 8)]);
                    O[df][0] = __builtin_amdgcn_mfma_f32_32x32x16_bf16(vfr, pf[0], O[df][0], 0, 0, 0);
                    O[df][1] = __builtin_amdgcn_mfma_f32_32x32x16_bf16(vfr, pf[1], O[df][1], 0, 0, 0);
                }
            }
        }
    }

    // epilogue: normalize, half-swap to row layout, store bf16 partial rows
    #pragma unroll
    for (int qi = 0; qi < 2; ++qi) {
        float l = lsum[qi];
        l += __shfl_xor(l, 32);
        float inv = 1.0f / l;
        #pragma unroll
        for (int r = 0; r < 16; ++r) { O[0][qi][r] *= inv; O[1][qi][r] *= inv; }

        unsigned short* dst = part + ((size_t)jj * 3 + i) * PLANE
            + (size_t)(b * N_DIM + q0 + wave * 64 + qi * 32 + lq) * 64 + h * 32;
        #pragma unroll
        for (int s = 0; s < 4; ++s) {
            unsigned t00 = pk_rne(O[0][qi][4 * s], O[0][qi][4 * s + 1]);
            unsigned t01 = pk_rne(O[0][qi][4 * s + 2], O[0][qi][4 * s + 3]);
            unsigned t10 = pk_rne(O[1][qi][4 * s], O[1][qi][4 * s + 1]);
            unsigned t11 = pk_rne(O[1][qi][4 * s + 2], O[1][qi][4 * s + 3]);
            u32x2 a = half_swap(t00, t10);
            u32x2 c = half_swap(t01, t11);
            uint4 w; w.x = a.x; w.y = c.x; w.z = a.y; w.w = c.y;
            *(uint4*)&dst[s * 8] = w;
        }
    }
}

// ---------------------------------------------------------------------------
// reduce: out = (1/3) * sum of 6 bf16 partial planes
// ---------------------------------------------------------------------------
__global__ __launch_bounds__(256) void reduce_kernel(
    const unsigned short* __restrict__ part, float* __restrict__ out)
{
    size_t e = ((size_t)blockIdx.x * 256 + threadIdx.x) * 4;
    float a0 = 0.f, a1 = 0.f, a2 = 0.f, a3 = 0.f;
    #pragma unroll
    for (int q = 0; q < 6; ++q) {
        const unsigned short* pp = part + (size_t)q * PLANE + e;
        unsigned u0 = *(const unsigned*)&pp[0];
        unsigned u1 = *(const unsigned*)&pp[2];
        a0 += __builtin_bit_cast(float, u0 << 16);
        a1 += __builtin_bit_cast(float, u0 & 0xffff0000u);
        a2 += __builtin_bit_cast(float, u1 << 16);
        a3 += __builtin_bit_cast(float, u1 & 0xffff0000u);
    }
    f32x4 v;
    v.x = a0 * (1.0f / 3.0f); v.y = a1 * (1.0f / 3.0f);
    v.z = a2 * (1.0f / 3.0f); v.w = a3 * (1.0f / 3.0f);
    *(f32x4*)&out[e] = v;
}

extern "C" void kernel_launch(void* const* d_in, const int* in_sizes, int n_in,
                              void* d_out, int out_size, void* d_ws, size_t ws_size,
                              hipStream_t stream)
{
    const float* x0 = (const float*)d_in[0];
    const float* x1 = (const float*)d_in[1];
    const float* x2 = (const float*)d_in[2];
    const float* w0 = (const float*)d_in[3];
    const float* w1 = (const float*)d_in[4];
    const float* w2 = (const float*)d_in[5];
    float* out = (float*)d_out;

    size_t nElem = (size_t)3 * BN * 64;     // 6,291,456 bf16 per tensor
    unsigned short* Qbf = (unsigned short*)d_ws;
    unsigned short* Kbf = Qbf + nElem;
    unsigned short* Vt  = Kbf + nElem;
    unsigned short* part = Vt + nElem;      // 6 planes * BN*64 bf16 = 25.2 MB

    hipLaunchKernelGGL(prep_kernel, dim3(3 * (BN / 128)), dim3(256), 0, stream,
                       x0, x1, x2, w0, w1, w2, Qbf, Kbf, Vt);
    hipLaunchKernelGGL(attn_kernel, dim3(6 * B_DIM * (N_DIM / 256)), dim3(256), 0, stream,
                       Qbf, Kbf, Vt, part);
    hipLaunchKernelGGL(reduce_kernel, dim3((BN * 64 / 4) / 256), dim3(256), 0, stream,
                       part, out);
}